// Round 1
// baseline (612.211 us; speedup 1.0000x reference)
//
#include <hip/hip_runtime.h>
#include <math.h>

// Problem constants (from reference): N=50000, E=800000, D=H=64, ED=16.
// Pipeline:
//   g   = (x @ W1) * dinv[row]          (node_gemm)
//   acc = g  (self-loop term)           (node_gemm writes both)
//   acc[d] += g[s]  per edge            (scatter, f32 atomics)
//   h = relu(dinv[row]*acc + b1)        (finalize_h, overwrites g)
//   out[e] = sigmoid(relu([h_s|h_d|ea] @ Wm1 + bm1) @ Wm2 + bm2)   (edge_mlp)

__global__ void deg_count(const int* __restrict__ dst, float* __restrict__ deg, int E) {
    int e = blockIdx.x * blockDim.x + threadIdx.x;
    if (e < E) atomicAdd(&deg[dst[e]], 1.0f);
}

__global__ void finish_dinv(float* __restrict__ deg, int N) {
    int i = blockIdx.x * blockDim.x + threadIdx.x;
    if (i < N) deg[i] = rsqrtf(deg[i] + 1.0f);   // +1 self loop; deg>0 always
}

__global__ void __launch_bounds__(256) node_gemm(
        const float* __restrict__ x, const float* __restrict__ W1,
        const float* __restrict__ dinv, float* __restrict__ g,
        float* __restrict__ acc, int N) {
    __shared__ float sW[64 * 64];
    for (int i = threadIdx.x; i < 64 * 64; i += blockDim.x) sW[i] = W1[i];
    __syncthreads();
    int i = blockIdx.x * blockDim.x + threadIdx.x;
    if (i >= N) return;
    float a[64];
#pragma unroll
    for (int j = 0; j < 64; ++j) a[j] = 0.0f;
    const float4* xr = (const float4*)(x + (size_t)i * 64);
#pragma unroll 1
    for (int k4 = 0; k4 < 16; ++k4) {
        float4 v = xr[k4];
        int k = k4 * 4;
#pragma unroll
        for (int j = 0; j < 64; ++j) {
            a[j] += v.x * sW[(k + 0) * 64 + j];
            a[j] += v.y * sW[(k + 1) * 64 + j];
            a[j] += v.z * sW[(k + 2) * 64 + j];
            a[j] += v.w * sW[(k + 3) * 64 + j];
        }
    }
    float di = dinv[i];
    float4* gp = (float4*)(g + (size_t)i * 64);
    float4* ap = (float4*)(acc + (size_t)i * 64);
#pragma unroll
    for (int j4 = 0; j4 < 16; ++j4) {
        float4 r;
        r.x = a[j4 * 4 + 0] * di;
        r.y = a[j4 * 4 + 1] * di;
        r.z = a[j4 * 4 + 2] * di;
        r.w = a[j4 * 4 + 3] * di;
        gp[j4] = r;
        ap[j4] = r;
    }
}

// one wave (64 lanes) per edge: lane c handles column c; coalesced row read +
// coalesced atomic row add
__global__ void scatter(const int* __restrict__ src, const int* __restrict__ dst,
                        const float* __restrict__ g, float* __restrict__ acc, int E) {
    long long idx = (long long)blockIdx.x * blockDim.x + threadIdx.x;
    int e = (int)(idx >> 6);
    int c = (int)(idx & 63);
    if (e >= E) return;
    int s = src[e], d = dst[e];
    atomicAdd(&acc[(size_t)d * 64 + c], g[(size_t)s * 64 + c]);
}

__global__ void finalize_h(const float* __restrict__ acc, const float* __restrict__ dinv,
                           const float* __restrict__ b1, float* __restrict__ h, int total) {
    int idx = blockIdx.x * blockDim.x + threadIdx.x;
    if (idx >= total) return;
    int i = idx >> 6, c = idx & 63;
    float v = dinv[i] * acc[idx] + b1[c];
    h[idx] = v > 0.0f ? v : 0.0f;
}

__global__ void __launch_bounds__(256) edge_mlp(
        const float* __restrict__ h, const float* __restrict__ ea,
        const int* __restrict__ src, const int* __restrict__ dst,
        const float* __restrict__ Wm1, const float* __restrict__ bm1,
        const float* __restrict__ Wm2, const float* __restrict__ bm2,
        float* __restrict__ out, int E) {
    __shared__ float sW[144 * 64];
    __shared__ float sW2[64];
    __shared__ float sb[64];
    for (int i = threadIdx.x; i < 144 * 64; i += blockDim.x) sW[i] = Wm1[i];
    if (threadIdx.x < 64) {
        sW2[threadIdx.x] = Wm2[threadIdx.x];
        sb[threadIdx.x]  = bm1[threadIdx.x];
    }
    __syncthreads();
    int e = blockIdx.x * blockDim.x + threadIdx.x;
    if (e >= E) return;
    int s = src[e], d = dst[e];
    float a[64];
#pragma unroll
    for (int j = 0; j < 64; ++j) a[j] = sb[j];

    const float4* hs = (const float4*)(h + (size_t)s * 64);
#pragma unroll 1
    for (int k4 = 0; k4 < 16; ++k4) {
        float4 v = hs[k4];
        int k = k4 * 4;
#pragma unroll
        for (int j = 0; j < 64; ++j) {
            a[j] += v.x * sW[(k + 0) * 64 + j];
            a[j] += v.y * sW[(k + 1) * 64 + j];
            a[j] += v.z * sW[(k + 2) * 64 + j];
            a[j] += v.w * sW[(k + 3) * 64 + j];
        }
    }
    const float4* hd = (const float4*)(h + (size_t)d * 64);
#pragma unroll 1
    for (int k4 = 0; k4 < 16; ++k4) {
        float4 v = hd[k4];
        int k = 64 + k4 * 4;
#pragma unroll
        for (int j = 0; j < 64; ++j) {
            a[j] += v.x * sW[(k + 0) * 64 + j];
            a[j] += v.y * sW[(k + 1) * 64 + j];
            a[j] += v.z * sW[(k + 2) * 64 + j];
            a[j] += v.w * sW[(k + 3) * 64 + j];
        }
    }
    const float4* ev = (const float4*)(ea + (size_t)e * 16);
#pragma unroll 1
    for (int k4 = 0; k4 < 4; ++k4) {
        float4 v = ev[k4];
        int k = 128 + k4 * 4;
#pragma unroll
        for (int j = 0; j < 64; ++j) {
            a[j] += v.x * sW[(k + 0) * 64 + j];
            a[j] += v.y * sW[(k + 1) * 64 + j];
            a[j] += v.z * sW[(k + 2) * 64 + j];
            a[j] += v.w * sW[(k + 3) * 64 + j];
        }
    }
    float sc = bm2[0];
#pragma unroll
    for (int j = 0; j < 64; ++j) {
        float r = a[j] > 0.0f ? a[j] : 0.0f;
        sc += r * sW2[j];
    }
    out[e] = 1.0f / (1.0f + __expf(-sc));
}

extern "C" void kernel_launch(void* const* d_in, const int* in_sizes, int n_in,
                              void* d_out, int out_size, void* d_ws, size_t ws_size,
                              hipStream_t stream) {
    const float* x   = (const float*)d_in[0];
    const int*   src = (const int*)d_in[1];
    const int*   dst = (const int*)d_in[2];
    const float* ea  = (const float*)d_in[3];
    const float* W1  = (const float*)d_in[4];
    const float* b1  = (const float*)d_in[5];
    const float* Wm1 = (const float*)d_in[6];
    const float* bm1 = (const float*)d_in[7];
    const float* Wm2 = (const float*)d_in[8];
    const float* bm2 = (const float*)d_in[9];
    float* out = (float*)d_out;

    const int N = in_sizes[0] / 64;   // 50000
    const int E = in_sizes[1];        // 800000

    // workspace layout: [dinv: 64K floats pad][g: N*64][acc: N*64]
    float* dinv = (float*)d_ws;
    float* g    = dinv + 65536;
    float* acc  = g + (size_t)N * 64;

    hipMemsetAsync(dinv, 0, (size_t)N * sizeof(float), stream);
    deg_count<<<(E + 255) / 256, 256, 0, stream>>>(dst, dinv, E);
    finish_dinv<<<(N + 255) / 256, 256, 0, stream>>>(dinv, N);
    node_gemm<<<(N + 255) / 256, 256, 0, stream>>>(x, W1, dinv, g, acc, N);
    {
        long long total = (long long)E * 64;
        int blocks = (int)((total + 255) / 256);
        scatter<<<blocks, 256, 0, stream>>>(src, dst, g, acc, E);
    }
    finalize_h<<<(N * 64 + 255) / 256, 256, 0, stream>>>(acc, dinv, b1, g, N * 64);
    edge_mlp<<<(E + 255) / 256, 256, 0, stream>>>(g, ea, src, dst, Wm1, bm1, Wm2, bm2, out, E);
}

// Round 2
// 406.691 us; speedup vs baseline: 1.5053x; 1.5053x over previous
//
#include <hip/hip_runtime.h>
#include <math.h>

// Problem constants: N=50000, E=800000, D=H=64, ED=16.
// Pipeline:
//   dinv = rsqrt(indeg+1)                         (deg_count + finish_dinv)
//   g    = (x @ W1) * dinv[row]; acc = g          (node_gemm, f32)
//   acc[d] += g[s]  per edge                      (scatter, f32 atomics)
//   hbf  = bf16(relu(dinv*acc + b1))              (finalize_h; hbf aliases g)
//   out[e] = sigmoid(relu([h_s|h_d|ea]@Wm1+bm1)@Wm2+bm2)  (edge_mlp_mfma, bf16 MFMA)

typedef __attribute__((ext_vector_type(8))) short bf16x8;
typedef __attribute__((ext_vector_type(4))) float f32x4;

__device__ __forceinline__ unsigned short f2b(float f) {
    unsigned u = __float_as_uint(f);
    unsigned r = (u + 0x7FFFu + ((u >> 16) & 1u)) >> 16;   // RNE
    return (unsigned short)r;
}

__global__ void deg_count(const int* __restrict__ dst, float* __restrict__ deg, int E) {
    int e = blockIdx.x * blockDim.x + threadIdx.x;
    if (e < E) atomicAdd(&deg[dst[e]], 1.0f);
}

__global__ void finish_dinv(float* __restrict__ deg, int N) {
    int i = blockIdx.x * blockDim.x + threadIdx.x;
    if (i < N) deg[i] = rsqrtf(deg[i] + 1.0f);
}

__global__ void __launch_bounds__(256) node_gemm(
        const float* __restrict__ x, const float* __restrict__ W1,
        const float* __restrict__ dinv, float* __restrict__ g,
        float* __restrict__ acc, int N) {
    __shared__ float sW[64 * 64];
    for (int i = threadIdx.x; i < 64 * 64; i += blockDim.x) sW[i] = W1[i];
    __syncthreads();
    int i = blockIdx.x * blockDim.x + threadIdx.x;
    if (i >= N) return;
    float a[64];
#pragma unroll
    for (int j = 0; j < 64; ++j) a[j] = 0.0f;
    const float4* xr = (const float4*)(x + (size_t)i * 64);
#pragma unroll 1
    for (int k4 = 0; k4 < 16; ++k4) {
        float4 v = xr[k4];
        int k = k4 * 4;
#pragma unroll
        for (int j = 0; j < 64; ++j) {
            a[j] += v.x * sW[(k + 0) * 64 + j];
            a[j] += v.y * sW[(k + 1) * 64 + j];
            a[j] += v.z * sW[(k + 2) * 64 + j];
            a[j] += v.w * sW[(k + 3) * 64 + j];
        }
    }
    float di = dinv[i];
    float4* gp = (float4*)(g + (size_t)i * 64);
    float4* ap = (float4*)(acc + (size_t)i * 64);
#pragma unroll
    for (int j4 = 0; j4 < 16; ++j4) {
        float4 r;
        r.x = a[j4 * 4 + 0] * di;
        r.y = a[j4 * 4 + 1] * di;
        r.z = a[j4 * 4 + 2] * di;
        r.w = a[j4 * 4 + 3] * di;
        gp[j4] = r;
        ap[j4] = r;
    }
}

__global__ void scatter(const int* __restrict__ src, const int* __restrict__ dst,
                        const float* __restrict__ g, float* __restrict__ acc, int E) {
    long long idx = (long long)blockIdx.x * blockDim.x + threadIdx.x;
    int e = (int)(idx >> 6);
    int c = (int)(idx & 63);
    if (e >= E) return;
    int s = src[e], d = dst[e];
    atomicAdd(&acc[(size_t)d * 64 + c], g[(size_t)s * 64 + c]);
}

// h -> bf16 (hbf may alias g: reads only acc/dinv/b1)
__global__ void finalize_h(const float* __restrict__ acc, const float* __restrict__ dinv,
                           const float* __restrict__ b1, unsigned short* __restrict__ hbf,
                           int total) {
    int idx = blockIdx.x * blockDim.x + threadIdx.x;
    if (idx >= total) return;
    int i = idx >> 6, c = idx & 63;
    float v = dinv[i] * acc[idx] + b1[c];
    hbf[idx] = f2b(v > 0.0f ? v : 0.0f);
}

// Pack Wm1 [144x64] f32 into bf16 B-fragment layout for mfma_f32_16x16x32_bf16.
// Bp[((s*4 + t)*64 + lane)*8 + j] = Wm1[k][col], k = s*32 + (lane>>4)*8 + j (0 if k>=144),
// col = t*16 + (lane&15). 5 K-steps (K padded 144->160), 4 N-tiles.
__global__ void pack_B(const float* __restrict__ Wm1, unsigned short* __restrict__ Bp) {
    int idx = blockIdx.x * blockDim.x + threadIdx.x;
    if (idx >= 5 * 4 * 64 * 8) return;
    int j = idx & 7, lane = (idx >> 3) & 63, t = (idx >> 9) & 3, s = idx >> 11;
    int quad = lane >> 4, n = lane & 15;
    int k = s * 32 + quad * 8 + j, col = t * 16 + n;
    float v = (k < 144) ? Wm1[k * 64 + col] : 0.0f;
    Bp[idx] = f2b(v);
}

// One wave per 16 edges. A[m][k] = concat(h[src],h[dst],ea,pad)[k] for edge m.
// A-frag: lane(m=lane&15, quad=lane>>4) holds A[m][k0+quad*8 .. +8] = 16B load.
// C/D: col=lane&15 (within N-tile), row=quad*4+reg (edge).
__global__ void __launch_bounds__(256) edge_mlp_mfma(
        const unsigned short* __restrict__ hbf, const float* __restrict__ ea,
        const int* __restrict__ src, const int* __restrict__ dst,
        const unsigned short* __restrict__ Bp,
        const float* __restrict__ bm1, const float* __restrict__ Wm2,
        const float* __restrict__ bm2, float* __restrict__ out, int E) {
    __shared__ unsigned short sB[5 * 4 * 64 * 8];   // 20 KB
    {
        const int4* gB = (const int4*)Bp;
        int4* lB = (int4*)sB;
#pragma unroll
        for (int i = 0; i < 5; ++i)    // 1280 int4 / 256 threads
            lB[threadIdx.x + i * 256] = gB[threadIdx.x + i * 256];
    }
    __syncthreads();

    int lane = threadIdx.x & 63;
    int wave = threadIdx.x >> 6;
    int m = lane & 15, quad = lane >> 4;
    int e0 = (blockIdx.x * 4 + wave) * 16;
    if (e0 >= E) return;
    int e = e0 + m;
    int ec = e < E ? e : E - 1;
    int si = src[ec], di = dst[ec];

    f32x4 acc[4];
#pragma unroll
    for (int t = 0; t < 4; ++t) acc[t] = (f32x4){0.f, 0.f, 0.f, 0.f};

    const bf16x8* bp = (const bf16x8*)sB;
#pragma unroll
    for (int s = 0; s < 5; ++s) {
        bf16x8 a;
        if (s < 2) {
            a = *(const bf16x8*)(hbf + (size_t)si * 64 + s * 32 + quad * 8);
        } else if (s < 4) {
            a = *(const bf16x8*)(hbf + (size_t)di * 64 + (s - 2) * 32 + quad * 8);
        } else {
            if (quad < 2) {
                const float4* ep = (const float4*)(ea + (size_t)ec * 16 + quad * 8);
                float4 v0 = ep[0], v1 = ep[1];
                a[0] = (short)f2b(v0.x); a[1] = (short)f2b(v0.y);
                a[2] = (short)f2b(v0.z); a[3] = (short)f2b(v0.w);
                a[4] = (short)f2b(v1.x); a[5] = (short)f2b(v1.y);
                a[6] = (short)f2b(v1.z); a[7] = (short)f2b(v1.w);
            } else {
#pragma unroll
                for (int j = 0; j < 8; ++j) a[j] = 0;
            }
        }
#pragma unroll
        for (int t = 0; t < 4; ++t)
            acc[t] = __builtin_amdgcn_mfma_f32_16x16x32_bf16(
                a, bp[(s * 4 + t) * 64 + lane], acc[t], 0, 0, 0);
    }

    // epilogue: +bm1, relu, dot with Wm2, reduce over the 16 col-lanes per quad
    float w2[4], bb[4];
#pragma unroll
    for (int t = 0; t < 4; ++t) {
        int col = t * 16 + m;
        bb[t] = bm1[col];
        w2[t] = Wm2[col];
    }
    float p[4];
#pragma unroll
    for (int r = 0; r < 4; ++r) {
        float sum = 0.0f;
#pragma unroll
        for (int t = 0; t < 4; ++t) {
            float hv = acc[t][r] + bb[t];
            sum += (hv > 0.0f ? hv : 0.0f) * w2[t];
        }
        p[r] = sum;
    }
#pragma unroll
    for (int off = 1; off < 16; off <<= 1) {
#pragma unroll
        for (int r = 0; r < 4; ++r) p[r] += __shfl_xor(p[r], off, 64);
    }
    float b2 = bm2[0];
    if (m < 4) {
        int eo = e0 + quad * 4 + m;
        if (eo < E) out[eo] = 1.0f / (1.0f + __expf(-(p[m] + b2)));
    }
}

extern "C" void kernel_launch(void* const* d_in, const int* in_sizes, int n_in,
                              void* d_out, int out_size, void* d_ws, size_t ws_size,
                              hipStream_t stream) {
    const float* x   = (const float*)d_in[0];
    const int*   src = (const int*)d_in[1];
    const int*   dst = (const int*)d_in[2];
    const float* ea  = (const float*)d_in[3];
    const float* W1  = (const float*)d_in[4];
    const float* b1  = (const float*)d_in[5];
    const float* Wm1 = (const float*)d_in[6];
    const float* bm1 = (const float*)d_in[7];
    const float* Wm2 = (const float*)d_in[8];
    const float* bm2 = (const float*)d_in[9];
    float* out = (float*)d_out;

    const int N = in_sizes[0] / 64;   // 50000
    const int E = in_sizes[1];        // 800000

    // ws layout: [dinv 64K f][g N*64 f (later aliased as hbf ushort)][acc N*64 f][Bp 10240 us]
    float* dinv = (float*)d_ws;
    float* g    = dinv + 65536;
    float* acc  = g + (size_t)N * 64;
    unsigned short* Bp = (unsigned short*)(acc + (size_t)N * 64);
    unsigned short* hbf = (unsigned short*)g;   // overwrites g after scatter

    hipMemsetAsync(dinv, 0, (size_t)N * sizeof(float), stream);
    pack_B<<<40, 256, 0, stream>>>(Wm1, Bp);
    deg_count<<<(E + 255) / 256, 256, 0, stream>>>(dst, dinv, E);
    finish_dinv<<<(N + 255) / 256, 256, 0, stream>>>(dinv, N);
    node_gemm<<<(N + 255) / 256, 256, 0, stream>>>(x, W1, dinv, g, acc, N);
    {
        long long total = (long long)E * 64;
        int blocks = (int)((total + 255) / 256);
        scatter<<<blocks, 256, 0, stream>>>(src, dst, g, acc, E);
    }
    finalize_h<<<(N * 64 + 255) / 256, 256, 0, stream>>>(acc, dinv, b1, hbf, N * 64);
    edge_mlp_mfma<<<(E + 63) / 64, 256, 0, stream>>>(hbf, ea, src, dst, Bp,
                                                     bm1, Wm2, bm2, out, E);
}

// Round 4
// 292.542 us; speedup vs baseline: 2.0927x; 1.3902x over previous
//
#include <hip/hip_runtime.h>
#include <math.h>

// Problem constants: N=50000, E=800000, D=H=64, ED=16.
// Pipeline (no f32 atomics on the hot path — CSR gather instead of scatter):
//   cnt[i]  = indegree(i)                         (hist, int atomics)
//   row_start = exclusive_scan(cnt)               (scan1/scan2/scan3)
//   dinv    = rsqrt(cnt+1)                        (fused into scan3)
//   csr     = src sorted by dst                   (fill, int atomics for slots)
//   g       = (x @ W1) * dinv[row]                (node_gemm, f32)
//   hbf[i]  = bf16(relu(dinv[i]*(g[i] + sum_{s->i} g[s]) + b1))   (gather_finalize)
//   out[e]  = sigmoid(relu([h_s|h_d|ea]@Wm1+bm1)@Wm2+bm2)         (edge_mlp_mfma)
//
// NOTE: hbf must NOT alias g — gather_finalize reads neighbor rows of g from
// arbitrary nodes while writing hbf (R2 aliasing bug: cross-block RW race).

typedef __attribute__((ext_vector_type(8))) short bf16x8;
typedef __attribute__((ext_vector_type(4))) float f32x4;

__device__ __forceinline__ unsigned short f2b(float f) {
    unsigned u = __float_as_uint(f);
    unsigned r = (u + 0x7FFFu + ((u >> 16) & 1u)) >> 16;   // RNE
    return (unsigned short)r;
}

__global__ void hist(const int* __restrict__ dst, int* __restrict__ cnt, int E) {
    int e = blockIdx.x * blockDim.x + threadIdx.x;
    if (e < E) atomicAdd(&cnt[dst[e]], 1);
}

// per-block exclusive scan; block totals to bsum
__global__ void scan1(const int* __restrict__ cnt, int* __restrict__ part,
                      int* __restrict__ bsum, int N) {
    __shared__ int s[256];
    int tid = threadIdx.x;
    int i = blockIdx.x * 256 + tid;
    int v = (i < N) ? cnt[i] : 0;
    s[tid] = v;
    __syncthreads();
#pragma unroll
    for (int off = 1; off < 256; off <<= 1) {
        int t = (tid >= off) ? s[tid - off] : 0;
        __syncthreads();
        s[tid] += t;
        __syncthreads();
    }
    if (i < N) part[i] = s[tid] - v;           // exclusive within block
    if (tid == 255) bsum[blockIdx.x] = s[255]; // block total
}

// exclusive scan of block sums (nb <= 256), in place
__global__ void scan2(int* __restrict__ bsum, int nb) {
    __shared__ int s[256];
    int tid = threadIdx.x;
    int v = (tid < nb) ? bsum[tid] : 0;
    s[tid] = v;
    __syncthreads();
#pragma unroll
    for (int off = 1; off < 256; off <<= 1) {
        int t = (tid >= off) ? s[tid - off] : 0;
        __syncthreads();
        s[tid] += t;
        __syncthreads();
    }
    if (tid < nb) bsum[tid] = s[tid] - v;
}

// row_start[i] = part[i] + bsum[blk]; cursor = copy; dinv = rsqrt(cnt+1)
__global__ void scan3(int* __restrict__ row_start, int* __restrict__ cursor,
                      const int* __restrict__ bsum, const int* __restrict__ cnt,
                      float* __restrict__ dinv, int N) {
    int i = blockIdx.x * 256 + threadIdx.x;
    if (i >= N) return;
    int rs = row_start[i] + bsum[blockIdx.x];
    row_start[i] = rs;
    cursor[i] = rs;
    dinv[i] = rsqrtf((float)cnt[i] + 1.0f);
    if (i == N - 1) row_start[N] = rs + cnt[i];
}

__global__ void fill(const int* __restrict__ src, const int* __restrict__ dst,
                     int* __restrict__ cursor, int* __restrict__ csr, int E) {
    int e = blockIdx.x * blockDim.x + threadIdx.x;
    if (e >= E) return;
    int pos = atomicAdd(&cursor[dst[e]], 1);
    csr[pos] = src[e];
}

__global__ void __launch_bounds__(256) node_gemm(
        const float* __restrict__ x, const float* __restrict__ W1,
        const float* __restrict__ dinv, float* __restrict__ g, int N) {
    __shared__ float sW[64 * 64];
    for (int i = threadIdx.x; i < 64 * 64; i += blockDim.x) sW[i] = W1[i];
    __syncthreads();
    int i = blockIdx.x * blockDim.x + threadIdx.x;
    if (i >= N) return;
    float a[64];
#pragma unroll
    for (int j = 0; j < 64; ++j) a[j] = 0.0f;
    const float4* xr = (const float4*)(x + (size_t)i * 64);
#pragma unroll 1
    for (int k4 = 0; k4 < 16; ++k4) {
        float4 v = xr[k4];
        int k = k4 * 4;
#pragma unroll
        for (int j = 0; j < 64; ++j) {
            a[j] += v.x * sW[(k + 0) * 64 + j];
            a[j] += v.y * sW[(k + 1) * 64 + j];
            a[j] += v.z * sW[(k + 2) * 64 + j];
            a[j] += v.w * sW[(k + 3) * 64 + j];
        }
    }
    float di = dinv[i];
    float4* gp = (float4*)(g + (size_t)i * 64);
#pragma unroll
    for (int j4 = 0; j4 < 16; ++j4) {
        float4 r;
        r.x = a[j4 * 4 + 0] * di;
        r.y = a[j4 * 4 + 1] * di;
        r.z = a[j4 * 4 + 2] * di;
        r.w = a[j4 * 4 + 3] * di;
        gp[j4] = r;
    }
}

// one wave per node: lane c accumulates column c over in-neighbors (CSR), then
// h = relu(dinv*acc + b1) -> bf16. Neighbor indices batch-loaded 64 at a time.
__global__ void __launch_bounds__(256) gather_finalize(
        const float* __restrict__ g, const int* __restrict__ csr,
        const int* __restrict__ row_start, const float* __restrict__ dinv,
        const float* __restrict__ b1, unsigned short* __restrict__ hbf, int N) {
    int wid = blockIdx.x * 4 + (threadIdx.x >> 6);
    if (wid >= N) return;
    int lane = threadIdx.x & 63;
    int base = row_start[wid];
    int deg = row_start[wid + 1] - base;
    float a0 = g[(size_t)wid * 64 + lane];   // self loop (already * dinv[wid])
    float a1 = 0.f, a2 = 0.f, a3 = 0.f;
    for (int j0 = 0; j0 < deg; j0 += 64) {
        int nidx = j0 + lane;
        int sidx = (nidx < deg) ? csr[base + nidx] : 0;
        int cnt = deg - j0;
        if (cnt > 64) cnt = 64;
        int j = 0;
        for (; j + 4 <= cnt; j += 4) {
            int s0 = __shfl(sidx, j, 64);
            int s1 = __shfl(sidx, j + 1, 64);
            int s2 = __shfl(sidx, j + 2, 64);
            int s3 = __shfl(sidx, j + 3, 64);
            a0 += g[(size_t)s0 * 64 + lane];
            a1 += g[(size_t)s1 * 64 + lane];
            a2 += g[(size_t)s2 * 64 + lane];
            a3 += g[(size_t)s3 * 64 + lane];
        }
        for (; j < cnt; ++j) {
            int s0 = __shfl(sidx, j, 64);
            a0 += g[(size_t)s0 * 64 + lane];
        }
    }
    float acc = (a0 + a1) + (a2 + a3);
    float hv = dinv[wid] * acc + b1[lane];
    hbf[(size_t)wid * 64 + lane] = f2b(hv > 0.0f ? hv : 0.0f);
}

// Pack Wm1 [144x64] f32 into bf16 B-fragment layout for mfma_f32_16x16x32_bf16.
__global__ void pack_B(const float* __restrict__ Wm1, unsigned short* __restrict__ Bp) {
    int idx = blockIdx.x * blockDim.x + threadIdx.x;
    if (idx >= 5 * 4 * 64 * 8) return;
    int j = idx & 7, lane = (idx >> 3) & 63, t = (idx >> 9) & 3, s = idx >> 11;
    int quad = lane >> 4, n = lane & 15;
    int k = s * 32 + quad * 8 + j, col = t * 16 + n;
    float v = (k < 144) ? Wm1[k * 64 + col] : 0.0f;
    Bp[idx] = f2b(v);
}

// One wave per 16 edges; bf16 MFMA over K=160 (144 padded), N-tiles 4x16.
__global__ void __launch_bounds__(256) edge_mlp_mfma(
        const unsigned short* __restrict__ hbf, const float* __restrict__ ea,
        const int* __restrict__ src, const int* __restrict__ dst,
        const unsigned short* __restrict__ Bp,
        const float* __restrict__ bm1, const float* __restrict__ Wm2,
        const float* __restrict__ bm2, float* __restrict__ out, int E) {
    __shared__ unsigned short sB[5 * 4 * 64 * 8];   // 20 KB
    {
        const int4* gB = (const int4*)Bp;
        int4* lB = (int4*)sB;
#pragma unroll
        for (int i = 0; i < 5; ++i)
            lB[threadIdx.x + i * 256] = gB[threadIdx.x + i * 256];
    }
    __syncthreads();

    int lane = threadIdx.x & 63;
    int wave = threadIdx.x >> 6;
    int m = lane & 15, quad = lane >> 4;
    int e0 = (blockIdx.x * 4 + wave) * 16;
    if (e0 >= E) return;
    int e = e0 + m;
    int ec = e < E ? e : E - 1;
    int si = src[ec], di = dst[ec];

    f32x4 acc[4];
#pragma unroll
    for (int t = 0; t < 4; ++t) acc[t] = (f32x4){0.f, 0.f, 0.f, 0.f};

    const bf16x8* bp = (const bf16x8*)sB;
#pragma unroll
    for (int s = 0; s < 5; ++s) {
        bf16x8 a;
        if (s < 2) {
            a = *(const bf16x8*)(hbf + (size_t)si * 64 + s * 32 + quad * 8);
        } else if (s < 4) {
            a = *(const bf16x8*)(hbf + (size_t)di * 64 + (s - 2) * 32 + quad * 8);
        } else {
            if (quad < 2) {
                const float4* ep = (const float4*)(ea + (size_t)ec * 16 + quad * 8);
                float4 v0 = ep[0], v1 = ep[1];
                a[0] = (short)f2b(v0.x); a[1] = (short)f2b(v0.y);
                a[2] = (short)f2b(v0.z); a[3] = (short)f2b(v0.w);
                a[4] = (short)f2b(v1.x); a[5] = (short)f2b(v1.y);
                a[6] = (short)f2b(v1.z); a[7] = (short)f2b(v1.w);
            } else {
#pragma unroll
                for (int j = 0; j < 8; ++j) a[j] = 0;
            }
        }
#pragma unroll
        for (int t = 0; t < 4; ++t)
            acc[t] = __builtin_amdgcn_mfma_f32_16x16x32_bf16(
                a, bp[(s * 4 + t) * 64 + lane], acc[t], 0, 0, 0);
    }

    float w2[4], bb[4];
#pragma unroll
    for (int t = 0; t < 4; ++t) {
        int col = t * 16 + m;
        bb[t] = bm1[col];
        w2[t] = Wm2[col];
    }
    float p[4];
#pragma unroll
    for (int r = 0; r < 4; ++r) {
        float sum = 0.0f;
#pragma unroll
        for (int t = 0; t < 4; ++t) {
            float hv = acc[t][r] + bb[t];
            sum += (hv > 0.0f ? hv : 0.0f) * w2[t];
        }
        p[r] = sum;
    }
#pragma unroll
    for (int off = 1; off < 16; off <<= 1) {
#pragma unroll
        for (int r = 0; r < 4; ++r) p[r] += __shfl_xor(p[r], off, 64);
    }
    float b2 = bm2[0];
    if (m < 4) {
        int eo = e0 + quad * 4 + m;
        if (eo < E) out[eo] = 1.0f / (1.0f + __expf(-(p[m] + b2)));
    }
}

extern "C" void kernel_launch(void* const* d_in, const int* in_sizes, int n_in,
                              void* d_out, int out_size, void* d_ws, size_t ws_size,
                              hipStream_t stream) {
    const float* x   = (const float*)d_in[0];
    const int*   src = (const int*)d_in[1];
    const int*   dst = (const int*)d_in[2];
    const float* ea  = (const float*)d_in[3];
    const float* W1  = (const float*)d_in[4];
    const float* b1  = (const float*)d_in[5];
    const float* Wm1 = (const float*)d_in[6];
    const float* bm1 = (const float*)d_in[7];
    const float* Wm2 = (const float*)d_in[8];
    const float* bm2 = (const float*)d_in[9];
    float* out = (float*)d_out;

    const int N = in_sizes[0] / 64;   // 50000
    const int E = in_sizes[1];        // 800000
    const int NB = (N + 255) / 256;   // 196 scan blocks

    // ws layout (4B units; hbf is a SEPARATE region, not aliasing g):
    float* g = (float*)d_ws;                            // N*64 f32   (12.8 MB)
    unsigned short* hbf = (unsigned short*)(g + (size_t)N * 64);   // N*64 bf16 (6.4 MB)
    int*   csr       = (int*)(hbf + (size_t)N * 64);    // E          (3.2 MB)
    int*   cnt       = csr + E;                         // N
    int*   row_start = cnt + N;                         // N+1
    int*   cursor    = row_start + N + 2;               // N
    int*   bsum      = cursor + N;                      // NB (<=256)
    float* dinv      = (float*)(bsum + 256);            // N
    unsigned short* Bp = (unsigned short*)(dinv + N);   // 10240

    hipMemsetAsync(cnt, 0, (size_t)N * sizeof(int), stream);
    pack_B<<<40, 256, 0, stream>>>(Wm1, Bp);
    hist<<<(E + 255) / 256, 256, 0, stream>>>(dst, cnt, E);
    scan1<<<NB, 256, 0, stream>>>(cnt, row_start, bsum, N);
    scan2<<<1, 256, 0, stream>>>(bsum, NB);
    scan3<<<NB, 256, 0, stream>>>(row_start, cursor, bsum, cnt, dinv, N);
    node_gemm<<<(N + 255) / 256, 256, 0, stream>>>(x, W1, dinv, g, N);
    fill<<<(E + 255) / 256, 256, 0, stream>>>(src, dst, cursor, csr, E);
    gather_finalize<<<(N + 3) / 4, 256, 0, stream>>>(g, csr, row_start, dinv, b1, hbf, N);
    edge_mlp_mfma<<<(E + 63) / 64, 256, 0, stream>>>(hbf, ea, src, dst, Bp,
                                                     bm1, Wm2, bm2, out, E);
}

// Round 5
// 269.565 us; speedup vs baseline: 2.2711x; 1.0852x over previous
//
#include <hip/hip_runtime.h>
#include <math.h>

// Problem constants: N=50000, E=800000, D=H=64, ED=16.
// Pipeline (CSR gather, bf16 g):
//   cnt/row_start/cursor/dinv  (hist + scan1/2/3, int atomics)
//   csr = src sorted by dst    (fill)
//   gbf = bf16((x @ W1) * dinv[row])              (node_gemm_mfma, bf16 MFMA)
//   hbf[i] = bf16(relu(dinv[i]*(gbf[i] + sum gbf[s]) + b1))  (gather_finalize, 2 nbrs/iter)
//   out[e] = sigmoid(relu([h_s|h_d|ea]@Wm1+bm1)@Wm2+bm2)     (edge_mlp_mfma, 32 edges/wave)
//
// NOTE: hbf must NOT alias gbf — gather reads arbitrary neighbor rows while writing hbf.

typedef __attribute__((ext_vector_type(8))) short bf16x8;
typedef __attribute__((ext_vector_type(4))) float f32x4;

__device__ __forceinline__ unsigned short f2b(float f) {
    unsigned u = __float_as_uint(f);
    unsigned r = (u + 0x7FFFu + ((u >> 16) & 1u)) >> 16;   // RNE
    return (unsigned short)r;
}

__global__ void hist(const int* __restrict__ dst, int* __restrict__ cnt, int E) {
    int e = blockIdx.x * blockDim.x + threadIdx.x;
    if (e < E) atomicAdd(&cnt[dst[e]], 1);
}

__global__ void scan1(const int* __restrict__ cnt, int* __restrict__ part,
                      int* __restrict__ bsum, int N) {
    __shared__ int s[256];
    int tid = threadIdx.x;
    int i = blockIdx.x * 256 + tid;
    int v = (i < N) ? cnt[i] : 0;
    s[tid] = v;
    __syncthreads();
#pragma unroll
    for (int off = 1; off < 256; off <<= 1) {
        int t = (tid >= off) ? s[tid - off] : 0;
        __syncthreads();
        s[tid] += t;
        __syncthreads();
    }
    if (i < N) part[i] = s[tid] - v;
    if (tid == 255) bsum[blockIdx.x] = s[255];
}

__global__ void scan2(int* __restrict__ bsum, int nb) {
    __shared__ int s[256];
    int tid = threadIdx.x;
    int v = (tid < nb) ? bsum[tid] : 0;
    s[tid] = v;
    __syncthreads();
#pragma unroll
    for (int off = 1; off < 256; off <<= 1) {
        int t = (tid >= off) ? s[tid - off] : 0;
        __syncthreads();
        s[tid] += t;
        __syncthreads();
    }
    if (tid < nb) bsum[tid] = s[tid] - v;
}

__global__ void scan3(int* __restrict__ row_start, int* __restrict__ cursor,
                      const int* __restrict__ bsum, const int* __restrict__ cnt,
                      float* __restrict__ dinv, int N) {
    int i = blockIdx.x * 256 + threadIdx.x;
    if (i >= N) return;
    int rs = row_start[i] + bsum[blockIdx.x];
    row_start[i] = rs;
    cursor[i] = rs;
    dinv[i] = rsqrtf((float)cnt[i] + 1.0f);
    if (i == N - 1) row_start[N] = rs + cnt[i];
}

__global__ void fill(const int* __restrict__ src, const int* __restrict__ dst,
                     int* __restrict__ cursor, int* __restrict__ csr, int E) {
    int e = blockIdx.x * blockDim.x + threadIdx.x;
    if (e >= E) return;
    int pos = atomicAdd(&cursor[dst[e]], 1);
    csr[pos] = src[e];
}

// Pack Wm1 [144x64] -> Bp (5 K-steps, K padded 160) and W1 [64x64] -> Bp1 (2 K-steps)
// in mfma_f32_16x16x32_bf16 B-fragment layout:
//   Bx[((s*4+t)*64 + lane)*8 + j] = W[k][col], k = s*32 + (lane>>4)*8 + j, col = t*16 + (lane&15)
__global__ void pack_B(const float* __restrict__ Wm1, const float* __restrict__ W1,
                       unsigned short* __restrict__ Bp, unsigned short* __restrict__ Bp1) {
    int idx = blockIdx.x * blockDim.x + threadIdx.x;
    if (idx < 5 * 4 * 64 * 8) {
        int j = idx & 7, lane = (idx >> 3) & 63, t = (idx >> 9) & 3, s = idx >> 11;
        int k = s * 32 + (lane >> 4) * 8 + j, col = t * 16 + (lane & 15);
        float v = (k < 144) ? Wm1[k * 64 + col] : 0.0f;
        Bp[idx] = f2b(v);
    } else {
        int idx2 = idx - 5 * 4 * 64 * 8;
        if (idx2 < 2 * 4 * 64 * 8) {
            int j = idx2 & 7, lane = (idx2 >> 3) & 63, t = (idx2 >> 9) & 3, s = idx2 >> 11;
            int k = s * 32 + (lane >> 4) * 8 + j, col = t * 16 + (lane & 15);
            Bp1[idx2] = f2b(W1[k * 64 + col]);
        }
    }
}

// MFMA node GEMM: wave per 16 rows, gbf[row] = bf16(dinv[row] * (x@W1)[row]).
__global__ void __launch_bounds__(256) node_gemm_mfma(
        const float* __restrict__ x, const unsigned short* __restrict__ Bp1,
        const float* __restrict__ dinv, unsigned short* __restrict__ gbf, int NW) {
    __shared__ unsigned short sB[2 * 4 * 64 * 8];   // 8 KB
    {
        const int4* gB = (const int4*)Bp1;
        int4* lB = (int4*)sB;
#pragma unroll
        for (int i = 0; i < 2; ++i)
            lB[threadIdx.x + i * 256] = gB[threadIdx.x + i * 256];
    }
    __syncthreads();
    int wid = blockIdx.x * 4 + (threadIdx.x >> 6);
    if (wid >= NW) return;
    int lane = threadIdx.x & 63, m = lane & 15, quad = lane >> 4;
    int r0 = wid * 16;
    f32x4 acc[4];
#pragma unroll
    for (int t = 0; t < 4; ++t) acc[t] = (f32x4){0.f, 0.f, 0.f, 0.f};
    const bf16x8* bp = (const bf16x8*)sB;
#pragma unroll
    for (int s = 0; s < 2; ++s) {
        const float4* xp = (const float4*)(x + (size_t)(r0 + m) * 64 + s * 32 + quad * 8);
        float4 v0 = xp[0], v1 = xp[1];
        bf16x8 a;
        a[0] = (short)f2b(v0.x); a[1] = (short)f2b(v0.y);
        a[2] = (short)f2b(v0.z); a[3] = (short)f2b(v0.w);
        a[4] = (short)f2b(v1.x); a[5] = (short)f2b(v1.y);
        a[6] = (short)f2b(v1.z); a[7] = (short)f2b(v1.w);
#pragma unroll
        for (int t = 0; t < 4; ++t)
            acc[t] = __builtin_amdgcn_mfma_f32_16x16x32_bf16(
                a, bp[(s * 4 + t) * 64 + lane], acc[t], 0, 0, 0);
    }
#pragma unroll
    for (int reg = 0; reg < 4; ++reg) {
        int row = r0 + quad * 4 + reg;
        float di = dinv[row];
#pragma unroll
        for (int t = 0; t < 4; ++t)
            gbf[(size_t)row * 64 + t * 16 + m] = f2b(acc[t][reg] * di);
    }
}

// wave per node; 2 neighbors per step (lane>>5 = neighbor parity, lane&31 = col pair)
__global__ void __launch_bounds__(256) gather_finalize(
        const unsigned int* __restrict__ gbf_u, const int* __restrict__ csr,
        const int* __restrict__ row_start, const float* __restrict__ dinv,
        const float* __restrict__ b1, unsigned int* __restrict__ hbf_u, int N) {
    int wid = blockIdx.x * 4 + (threadIdx.x >> 6);
    if (wid >= N) return;
    int lane = threadIdx.x & 63;
    int which = lane >> 5, c2 = lane & 31;
    int base = row_start[wid];
    int deg = row_start[wid + 1] - base;
    float a0 = 0.f, a1 = 0.f;
    if (which == 0) {   // self loop row
        unsigned u = gbf_u[(size_t)wid * 32 + c2];
        a0 += __uint_as_float(u << 16);
        a1 += __uint_as_float(u & 0xffff0000u);
    }
    for (int j0 = 0; j0 < deg; j0 += 64) {
        int nidx = j0 + lane;
        int sidx = (nidx < deg) ? csr[base + nidx] : 0;
        int cnt = deg - j0; if (cnt > 64) cnt = 64;
        int full = cnt >> 1;
        int p = 0;
        for (; p + 4 <= full; p += 4) {
            int n0 = __shfl(sidx, (p + 0) * 2 + which, 64);
            int n1 = __shfl(sidx, (p + 1) * 2 + which, 64);
            int n2 = __shfl(sidx, (p + 2) * 2 + which, 64);
            int n3 = __shfl(sidx, (p + 3) * 2 + which, 64);
            unsigned u0 = gbf_u[(size_t)n0 * 32 + c2];
            unsigned u1 = gbf_u[(size_t)n1 * 32 + c2];
            unsigned u2 = gbf_u[(size_t)n2 * 32 + c2];
            unsigned u3 = gbf_u[(size_t)n3 * 32 + c2];
            a0 += __uint_as_float(u0 << 16) + __uint_as_float(u1 << 16)
                + __uint_as_float(u2 << 16) + __uint_as_float(u3 << 16);
            a1 += __uint_as_float(u0 & 0xffff0000u) + __uint_as_float(u1 & 0xffff0000u)
                + __uint_as_float(u2 & 0xffff0000u) + __uint_as_float(u3 & 0xffff0000u);
        }
        for (; p < full; ++p) {
            int n = __shfl(sidx, p * 2 + which, 64);
            unsigned u = gbf_u[(size_t)n * 32 + c2];
            a0 += __uint_as_float(u << 16);
            a1 += __uint_as_float(u & 0xffff0000u);
        }
        if (cnt & 1) {
            int n = __shfl(sidx, cnt - 1, 64);
            if (which == 0) {
                unsigned u = gbf_u[(size_t)n * 32 + c2];
                a0 += __uint_as_float(u << 16);
                a1 += __uint_as_float(u & 0xffff0000u);
            }
        }
    }
    a0 += __shfl_xor(a0, 32, 64);
    a1 += __shfl_xor(a1, 32, 64);
    if (which == 0) {
        float di = dinv[wid];
        float h0 = di * a0 + b1[2 * c2];
        float h1 = di * a1 + b1[2 * c2 + 1];
        h0 = h0 > 0.f ? h0 : 0.f;
        h1 = h1 > 0.f ? h1 : 0.f;
        hbf_u[(size_t)wid * 32 + c2] = (unsigned)f2b(h0) | ((unsigned)f2b(h1) << 16);
    }
}

__device__ __forceinline__ bf16x8 load_afrag(
        const unsigned short* __restrict__ hbf, const float* __restrict__ ea,
        int s, int si, int di, int ec, int quad) {
    bf16x8 a;
    if (s < 2) {
        a = *(const bf16x8*)(hbf + (size_t)si * 64 + s * 32 + quad * 8);
    } else if (s < 4) {
        a = *(const bf16x8*)(hbf + (size_t)di * 64 + (s - 2) * 32 + quad * 8);
    } else if (quad < 2) {
        const float4* ep = (const float4*)(ea + (size_t)ec * 16 + quad * 8);
        float4 v0 = ep[0], v1 = ep[1];
        a[0] = (short)f2b(v0.x); a[1] = (short)f2b(v0.y);
        a[2] = (short)f2b(v0.z); a[3] = (short)f2b(v0.w);
        a[4] = (short)f2b(v1.x); a[5] = (short)f2b(v1.y);
        a[6] = (short)f2b(v1.z); a[7] = (short)f2b(v1.w);
    } else {
#pragma unroll
        for (int j = 0; j < 8; ++j) a[j] = 0;
    }
    return a;
}

// 32 edges per wave (two 16x16 M-tiles sharing B-frags); K=160, 4 N-tiles.
__global__ void __launch_bounds__(256) edge_mlp_mfma(
        const unsigned short* __restrict__ hbf, const float* __restrict__ ea,
        const int* __restrict__ src, const int* __restrict__ dst,
        const unsigned short* __restrict__ Bp,
        const float* __restrict__ bm1, const float* __restrict__ Wm2,
        const float* __restrict__ bm2, float* __restrict__ out, int E) {
    __shared__ unsigned short sB[5 * 4 * 64 * 8];   // 20 KB
    {
        const int4* gB = (const int4*)Bp;
        int4* lB = (int4*)sB;
#pragma unroll
        for (int i = 0; i < 5; ++i)
            lB[threadIdx.x + i * 256] = gB[threadIdx.x + i * 256];
    }
    __syncthreads();

    int lane = threadIdx.x & 63;
    int wave = threadIdx.x >> 6;
    int m = lane & 15, quad = lane >> 4;
    int e0 = (blockIdx.x * 4 + wave) * 32;
    if (e0 >= E) return;
    int ea0 = e0 + m, ea1 = e0 + 16 + m;
    int ec0 = ea0 < E ? ea0 : E - 1;
    int ec1 = ea1 < E ? ea1 : E - 1;
    int si0 = src[ec0], di0 = dst[ec0];
    int si1 = src[ec1], di1 = dst[ec1];

    f32x4 acc0[4], acc1[4];
#pragma unroll
    for (int t = 0; t < 4; ++t) {
        acc0[t] = (f32x4){0.f, 0.f, 0.f, 0.f};
        acc1[t] = (f32x4){0.f, 0.f, 0.f, 0.f};
    }
    const bf16x8* bp = (const bf16x8*)sB;
#pragma unroll
    for (int s = 0; s < 5; ++s) {
        bf16x8 a0 = load_afrag(hbf, ea, s, si0, di0, ec0, quad);
        bf16x8 a1 = load_afrag(hbf, ea, s, si1, di1, ec1, quad);
#pragma unroll
        for (int t = 0; t < 4; ++t) {
            bf16x8 b = bp[(s * 4 + t) * 64 + lane];
            acc0[t] = __builtin_amdgcn_mfma_f32_16x16x32_bf16(a0, b, acc0[t], 0, 0, 0);
            acc1[t] = __builtin_amdgcn_mfma_f32_16x16x32_bf16(a1, b, acc1[t], 0, 0, 0);
        }
    }

    float w2[4], bb[4];
#pragma unroll
    for (int t = 0; t < 4; ++t) {
        int col = t * 16 + m;
        bb[t] = bm1[col];
        w2[t] = Wm2[col];
    }
    float b2 = bm2[0];
#pragma unroll
    for (int u = 0; u < 2; ++u) {
        f32x4* acc = u ? acc1 : acc0;
        float p[4];
#pragma unroll
        for (int r = 0; r < 4; ++r) {
            float sum = 0.0f;
#pragma unroll
            for (int t = 0; t < 4; ++t) {
                float hv = acc[t][r] + bb[t];
                sum += (hv > 0.0f ? hv : 0.0f) * w2[t];
            }
            p[r] = sum;
        }
#pragma unroll
        for (int off = 1; off < 16; off <<= 1) {
#pragma unroll
            for (int r = 0; r < 4; ++r) p[r] += __shfl_xor(p[r], off, 64);
        }
        if (m < 4) {
            int eo = e0 + u * 16 + quad * 4 + m;
            if (eo < E) out[eo] = 1.0f / (1.0f + __expf(-(p[m] + b2)));
        }
    }
}

extern "C" void kernel_launch(void* const* d_in, const int* in_sizes, int n_in,
                              void* d_out, int out_size, void* d_ws, size_t ws_size,
                              hipStream_t stream) {
    const float* x   = (const float*)d_in[0];
    const int*   src = (const int*)d_in[1];
    const int*   dst = (const int*)d_in[2];
    const float* ea  = (const float*)d_in[3];
    const float* W1  = (const float*)d_in[4];
    const float* b1  = (const float*)d_in[5];
    const float* Wm1 = (const float*)d_in[6];
    const float* bm1 = (const float*)d_in[7];
    const float* Wm2 = (const float*)d_in[8];
    const float* bm2 = (const float*)d_in[9];
    float* out = (float*)d_out;

    const int N = in_sizes[0] / 64;   // 50000
    const int E = in_sizes[1];        // 800000
    const int NB = (N + 255) / 256;   // 196
    const int NW = N / 16;            // 3125 node-gemm waves (50000 % 16 == 0)

    // ws layout (all chunks 256B-aligned):
    unsigned short* gbf = (unsigned short*)d_ws;            // N*64 bf16 (6.4 MB)
    unsigned short* hbf = gbf + (size_t)N * 64;             // N*64 bf16 (6.4 MB)
    int*   csr       = (int*)(hbf + (size_t)N * 64);        // E
    int*   cnt       = csr + E;                             // N
    int*   row_start = cnt + N;                             // N+1
    int*   cursor    = row_start + N + 2;                   // N
    int*   bsum      = cursor + N;                          // 256
    float* dinv      = (float*)(bsum + 256);                // N
    unsigned short* Bp  = (unsigned short*)(dinv + N);      // 10240
    unsigned short* Bp1 = Bp + 10240;                       // 4096

    hipMemsetAsync(cnt, 0, (size_t)N * sizeof(int), stream);
    pack_B<<<56, 256, 0, stream>>>(Wm1, W1, Bp, Bp1);
    hist<<<(E + 255) / 256, 256, 0, stream>>>(dst, cnt, E);
    scan1<<<NB, 256, 0, stream>>>(cnt, row_start, bsum, N);
    scan2<<<1, 256, 0, stream>>>(bsum, NB);
    scan3<<<NB, 256, 0, stream>>>(row_start, cursor, bsum, cnt, dinv, N);
    fill<<<(E + 255) / 256, 256, 0, stream>>>(src, dst, cursor, csr, E);
    node_gemm_mfma<<<(NW + 3) / 4, 256, 0, stream>>>(x, Bp1, dinv, gbf, NW);
    gather_finalize<<<(N + 3) / 4, 256, 0, stream>>>((const unsigned int*)gbf, csr,
                                                     row_start, dinv, b1,
                                                     (unsigned int*)hbf, N);
    edge_mlp_mfma<<<(E + 127) / 128, 256, 0, stream>>>(hbf, ea, src, dst, Bp,
                                                       bm1, Wm2, bm2, out, E);
}

// Round 6
// 255.890 us; speedup vs baseline: 2.3925x; 1.0534x over previous
//
#include <hip/hip_runtime.h>
#include <math.h>

// Problem constants: N=50000, E=800000, D=H=64, ED=16.
// Pipeline (CSR gather, bf16 g, atomic-free fill):
//   cnt[i]=indeg, rank[e]=arrival order  (hist — atomicAdd return IS the rank)
//   row_start = exscan(cnt); dinv = rsqrt(cnt+1)   (scan1/2/3)
//   csr[row_start[dst]+rank] = src                 (fill, NO atomics)
//   gbf = bf16((x @ W1) * dinv[row])               (node_gemm_mfma)
//   hbf[i] = bf16(relu(dinv[i]*(gbf[i] + sum gbf[s]) + b1))  (gather_finalize)
//   out[e] = sigmoid(relu([h_s|h_d|ea]@Wm1+bm1)@Wm2+bm2)     (edge_mlp_mfma, grid-stride)
//
// NOTE: hbf must NOT alias gbf — gather reads arbitrary neighbor rows while writing hbf.

typedef __attribute__((ext_vector_type(8))) short bf16x8;
typedef __attribute__((ext_vector_type(4))) float f32x4;

__device__ __forceinline__ unsigned short f2b(float f) {
    unsigned u = __float_as_uint(f);
    unsigned r = (u + 0x7FFFu + ((u >> 16) & 1u)) >> 16;   // RNE
    return (unsigned short)r;
}

__global__ void hist(const int* __restrict__ dst, int* __restrict__ cnt,
                     int* __restrict__ rank, int E) {
    int e = blockIdx.x * blockDim.x + threadIdx.x;
    if (e < E) rank[e] = atomicAdd(&cnt[dst[e]], 1);
}

__global__ void scan1(const int* __restrict__ cnt, int* __restrict__ part,
                      int* __restrict__ bsum, int N) {
    __shared__ int s[256];
    int tid = threadIdx.x;
    int i = blockIdx.x * 256 + tid;
    int v = (i < N) ? cnt[i] : 0;
    s[tid] = v;
    __syncthreads();
#pragma unroll
    for (int off = 1; off < 256; off <<= 1) {
        int t = (tid >= off) ? s[tid - off] : 0;
        __syncthreads();
        s[tid] += t;
        __syncthreads();
    }
    if (i < N) part[i] = s[tid] - v;
    if (tid == 255) bsum[blockIdx.x] = s[255];
}

__global__ void scan2(int* __restrict__ bsum, int nb) {
    __shared__ int s[256];
    int tid = threadIdx.x;
    int v = (tid < nb) ? bsum[tid] : 0;
    s[tid] = v;
    __syncthreads();
#pragma unroll
    for (int off = 1; off < 256; off <<= 1) {
        int t = (tid >= off) ? s[tid - off] : 0;
        __syncthreads();
        s[tid] += t;
        __syncthreads();
    }
    if (tid < nb) bsum[tid] = s[tid] - v;
}

__global__ void scan3(int* __restrict__ row_start, const int* __restrict__ bsum,
                      const int* __restrict__ cnt, float* __restrict__ dinv, int N) {
    int i = blockIdx.x * 256 + threadIdx.x;
    if (i >= N) return;
    int rs = row_start[i] + bsum[blockIdx.x];
    row_start[i] = rs;
    dinv[i] = rsqrtf((float)cnt[i] + 1.0f);
    if (i == N - 1) row_start[N] = rs + cnt[i];
}

// atomic-free: unique slot = row_start[dst] + rank
__global__ void fill(const int* __restrict__ src, const int* __restrict__ dst,
                     const int* __restrict__ rank, const int* __restrict__ row_start,
                     int* __restrict__ csr, int E) {
    int e = blockIdx.x * blockDim.x + threadIdx.x;
    if (e >= E) return;
    csr[row_start[dst[e]] + rank[e]] = src[e];
}

// Pack Wm1 [144x64] -> Bp (5 K-steps, K padded 160) and W1 [64x64] -> Bp1 (2 K-steps)
// in mfma_f32_16x16x32_bf16 B-fragment layout.
__global__ void pack_B(const float* __restrict__ Wm1, const float* __restrict__ W1,
                       unsigned short* __restrict__ Bp, unsigned short* __restrict__ Bp1) {
    int idx = blockIdx.x * blockDim.x + threadIdx.x;
    if (idx < 5 * 4 * 64 * 8) {
        int j = idx & 7, lane = (idx >> 3) & 63, t = (idx >> 9) & 3, s = idx >> 11;
        int k = s * 32 + (lane >> 4) * 8 + j, col = t * 16 + (lane & 15);
        float v = (k < 144) ? Wm1[k * 64 + col] : 0.0f;
        Bp[idx] = f2b(v);
    } else {
        int idx2 = idx - 5 * 4 * 64 * 8;
        if (idx2 < 2 * 4 * 64 * 8) {
            int j = idx2 & 7, lane = (idx2 >> 3) & 63, t = (idx2 >> 9) & 3, s = idx2 >> 11;
            int k = s * 32 + (lane >> 4) * 8 + j, col = t * 16 + (lane & 15);
            Bp1[idx2] = f2b(W1[k * 64 + col]);
        }
    }
}

__global__ void __launch_bounds__(256) node_gemm_mfma(
        const float* __restrict__ x, const unsigned short* __restrict__ Bp1,
        const float* __restrict__ dinv, unsigned short* __restrict__ gbf, int NW) {
    __shared__ unsigned short sB[2 * 4 * 64 * 8];   // 8 KB
    {
        const int4* gB = (const int4*)Bp1;
        int4* lB = (int4*)sB;
#pragma unroll
        for (int i = 0; i < 2; ++i)
            lB[threadIdx.x + i * 256] = gB[threadIdx.x + i * 256];
    }
    __syncthreads();
    int wid = blockIdx.x * 4 + (threadIdx.x >> 6);
    if (wid >= NW) return;
    int lane = threadIdx.x & 63, m = lane & 15, quad = lane >> 4;
    int r0 = wid * 16;
    f32x4 acc[4];
#pragma unroll
    for (int t = 0; t < 4; ++t) acc[t] = (f32x4){0.f, 0.f, 0.f, 0.f};
    const bf16x8* bp = (const bf16x8*)sB;
#pragma unroll
    for (int s = 0; s < 2; ++s) {
        const float4* xp = (const float4*)(x + (size_t)(r0 + m) * 64 + s * 32 + quad * 8);
        float4 v0 = xp[0], v1 = xp[1];
        bf16x8 a;
        a[0] = (short)f2b(v0.x); a[1] = (short)f2b(v0.y);
        a[2] = (short)f2b(v0.z); a[3] = (short)f2b(v0.w);
        a[4] = (short)f2b(v1.x); a[5] = (short)f2b(v1.y);
        a[6] = (short)f2b(v1.z); a[7] = (short)f2b(v1.w);
#pragma unroll
        for (int t = 0; t < 4; ++t)
            acc[t] = __builtin_amdgcn_mfma_f32_16x16x32_bf16(
                a, bp[(s * 4 + t) * 64 + lane], acc[t], 0, 0, 0);
    }
#pragma unroll
    for (int reg = 0; reg < 4; ++reg) {
        int row = r0 + quad * 4 + reg;
        float di = dinv[row];
#pragma unroll
        for (int t = 0; t < 4; ++t)
            gbf[(size_t)row * 64 + t * 16 + m] = f2b(acc[t][reg] * di);
    }
}

// wave per node; 2 neighbors per step (lane>>5 = neighbor parity, lane&31 = col pair)
__global__ void __launch_bounds__(256) gather_finalize(
        const unsigned int* __restrict__ gbf_u, const int* __restrict__ csr,
        const int* __restrict__ row_start, const float* __restrict__ dinv,
        const float* __restrict__ b1, unsigned int* __restrict__ hbf_u, int N) {
    int wid = blockIdx.x * 4 + (threadIdx.x >> 6);
    if (wid >= N) return;
    int lane = threadIdx.x & 63;
    int which = lane >> 5, c2 = lane & 31;
    int base = row_start[wid];
    int deg = row_start[wid + 1] - base;
    float a0 = 0.f, a1 = 0.f;
    if (which == 0) {   // self loop row
        unsigned u = gbf_u[(size_t)wid * 32 + c2];
        a0 += __uint_as_float(u << 16);
        a1 += __uint_as_float(u & 0xffff0000u);
    }
    for (int j0 = 0; j0 < deg; j0 += 64) {
        int nidx = j0 + lane;
        int sidx = (nidx < deg) ? csr[base + nidx] : 0;
        int cnt = deg - j0; if (cnt > 64) cnt = 64;
        int full = cnt >> 1;
        int p = 0;
        for (; p + 4 <= full; p += 4) {
            int n0 = __shfl(sidx, (p + 0) * 2 + which, 64);
            int n1 = __shfl(sidx, (p + 1) * 2 + which, 64);
            int n2 = __shfl(sidx, (p + 2) * 2 + which, 64);
            int n3 = __shfl(sidx, (p + 3) * 2 + which, 64);
            unsigned u0 = gbf_u[(size_t)n0 * 32 + c2];
            unsigned u1 = gbf_u[(size_t)n1 * 32 + c2];
            unsigned u2 = gbf_u[(size_t)n2 * 32 + c2];
            unsigned u3 = gbf_u[(size_t)n3 * 32 + c2];
            a0 += __uint_as_float(u0 << 16) + __uint_as_float(u1 << 16)
                + __uint_as_float(u2 << 16) + __uint_as_float(u3 << 16);
            a1 += __uint_as_float(u0 & 0xffff0000u) + __uint_as_float(u1 & 0xffff0000u)
                + __uint_as_float(u2 & 0xffff0000u) + __uint_as_float(u3 & 0xffff0000u);
        }
        for (; p < full; ++p) {
            int n = __shfl(sidx, p * 2 + which, 64);
            unsigned u = gbf_u[(size_t)n * 32 + c2];
            a0 += __uint_as_float(u << 16);
            a1 += __uint_as_float(u & 0xffff0000u);
        }
        if (cnt & 1) {
            int n = __shfl(sidx, cnt - 1, 64);
            if (which == 0) {
                unsigned u = gbf_u[(size_t)n * 32 + c2];
                a0 += __uint_as_float(u << 16);
                a1 += __uint_as_float(u & 0xffff0000u);
            }
        }
    }
    a0 += __shfl_xor(a0, 32, 64);
    a1 += __shfl_xor(a1, 32, 64);
    if (which == 0) {
        float di = dinv[wid];
        float h0 = di * a0 + b1[2 * c2];
        float h1 = di * a1 + b1[2 * c2 + 1];
        h0 = h0 > 0.f ? h0 : 0.f;
        h1 = h1 > 0.f ? h1 : 0.f;
        hbf_u[(size_t)wid * 32 + c2] = (unsigned)f2b(h0) | ((unsigned)f2b(h1) << 16);
    }
}

__device__ __forceinline__ bf16x8 load_afrag(
        const unsigned short* __restrict__ hbf, const float* __restrict__ ea,
        int s, int si, int di, int ec, int quad) {
    bf16x8 a;
    if (s < 2) {
        a = *(const bf16x8*)(hbf + (size_t)si * 64 + s * 32 + quad * 8);
    } else if (s < 4) {
        a = *(const bf16x8*)(hbf + (size_t)di * 64 + (s - 2) * 32 + quad * 8);
    } else if (quad < 2) {
        const float4* ep = (const float4*)(ea + (size_t)ec * 16 + quad * 8);
        float4 v0 = ep[0], v1 = ep[1];
        a[0] = (short)f2b(v0.x); a[1] = (short)f2b(v0.y);
        a[2] = (short)f2b(v0.z); a[3] = (short)f2b(v0.w);
        a[4] = (short)f2b(v1.x); a[5] = (short)f2b(v1.y);
        a[6] = (short)f2b(v1.z); a[7] = (short)f2b(v1.w);
    } else {
#pragma unroll
        for (int j = 0; j < 8; ++j) a[j] = 0;
    }
    return a;
}

// Grid-stride: each wave loops over groups of 32 edges (two 16x16 M-tiles
// sharing B-frags), amortizing the 20 KB LDS staging across ~5 groups.
__global__ void __launch_bounds__(256) edge_mlp_mfma(
        const unsigned short* __restrict__ hbf, const float* __restrict__ ea,
        const int* __restrict__ src, const int* __restrict__ dst,
        const unsigned short* __restrict__ Bp,
        const float* __restrict__ bm1, const float* __restrict__ Wm2,
        const float* __restrict__ bm2, float* __restrict__ out, int E) {
    __shared__ unsigned short sB[5 * 4 * 64 * 8];   // 20 KB
    {
        const int4* gB = (const int4*)Bp;
        int4* lB = (int4*)sB;
#pragma unroll
        for (int i = 0; i < 5; ++i)
            lB[threadIdx.x + i * 256] = gB[threadIdx.x + i * 256];
    }
    __syncthreads();

    int lane = threadIdx.x & 63;
    int wave = threadIdx.x >> 6;
    int m = lane & 15, quad = lane >> 4;
    const bf16x8* bp = (const bf16x8*)sB;

    float w2[4], bb[4];
#pragma unroll
    for (int t = 0; t < 4; ++t) {
        int col = t * 16 + m;
        bb[t] = bm1[col];
        w2[t] = Wm2[col];
    }
    float b2 = bm2[0];

    int gwave = blockIdx.x * 4 + wave;
    int nwaves = gridDim.x * 4;
    int ngroups = (E + 31) / 32;

    for (int grp = gwave; grp < ngroups; grp += nwaves) {
        int e0 = grp * 32;
        int ea0 = e0 + m, ea1 = e0 + 16 + m;
        int ec0 = ea0 < E ? ea0 : E - 1;
        int ec1 = ea1 < E ? ea1 : E - 1;
        int si0 = src[ec0], di0 = dst[ec0];
        int si1 = src[ec1], di1 = dst[ec1];

        f32x4 acc0[4], acc1[4];
#pragma unroll
        for (int t = 0; t < 4; ++t) {
            acc0[t] = (f32x4){0.f, 0.f, 0.f, 0.f};
            acc1[t] = (f32x4){0.f, 0.f, 0.f, 0.f};
        }
#pragma unroll
        for (int s = 0; s < 5; ++s) {
            bf16x8 a0 = load_afrag(hbf, ea, s, si0, di0, ec0, quad);
            bf16x8 a1 = load_afrag(hbf, ea, s, si1, di1, ec1, quad);
#pragma unroll
            for (int t = 0; t < 4; ++t) {
                bf16x8 b = bp[(s * 4 + t) * 64 + lane];
                acc0[t] = __builtin_amdgcn_mfma_f32_16x16x32_bf16(a0, b, acc0[t], 0, 0, 0);
                acc1[t] = __builtin_amdgcn_mfma_f32_16x16x32_bf16(a1, b, acc1[t], 0, 0, 0);
            }
        }

#pragma unroll
        for (int u = 0; u < 2; ++u) {
            f32x4* acc = u ? acc1 : acc0;
            float p[4];
#pragma unroll
            for (int r = 0; r < 4; ++r) {
                float sum = 0.0f;
#pragma unroll
                for (int t = 0; t < 4; ++t) {
                    float hv = acc[t][r] + bb[t];
                    sum += (hv > 0.0f ? hv : 0.0f) * w2[t];
                }
                p[r] = sum;
            }
#pragma unroll
            for (int off = 1; off < 16; off <<= 1) {
#pragma unroll
                for (int r = 0; r < 4; ++r) p[r] += __shfl_xor(p[r], off, 64);
            }
            if (m < 4) {
                int eo = e0 + u * 16 + quad * 4 + m;
                if (eo < E) out[eo] = 1.0f / (1.0f + __expf(-(p[m] + b2)));
            }
        }
    }
}

extern "C" void kernel_launch(void* const* d_in, const int* in_sizes, int n_in,
                              void* d_out, int out_size, void* d_ws, size_t ws_size,
                              hipStream_t stream) {
    const float* x   = (const float*)d_in[0];
    const int*   src = (const int*)d_in[1];
    const int*   dst = (const int*)d_in[2];
    const float* ea  = (const float*)d_in[3];
    const float* W1  = (const float*)d_in[4];
    const float* b1  = (const float*)d_in[5];
    const float* Wm1 = (const float*)d_in[6];
    const float* bm1 = (const float*)d_in[7];
    const float* Wm2 = (const float*)d_in[8];
    const float* bm2 = (const float*)d_in[9];
    float* out = (float*)d_out;

    const int N = in_sizes[0] / 64;   // 50000
    const int E = in_sizes[1];        // 800000
    const int NB = (N + 255) / 256;   // 196
    const int NW = N / 16;            // 3125

    // ws layout (all chunks 256B-aligned):
    unsigned short* gbf = (unsigned short*)d_ws;            // N*64 bf16 (6.4 MB)
    unsigned short* hbf = gbf + (size_t)N * 64;             // N*64 bf16 (6.4 MB)
    int*   csr       = (int*)(hbf + (size_t)N * 64);        // E  (3.2 MB)
    int*   rank      = csr + E;                             // E  (3.2 MB)
    int*   cnt       = rank + E;                            // N
    int*   row_start = cnt + N;                             // N+1
    int*   bsum      = row_start + N + 2;                   // 256
    float* dinv      = (float*)(bsum + 256);                // N
    unsigned short* Bp  = (unsigned short*)(dinv + N);      // 10240
    unsigned short* Bp1 = Bp + 10240;                       // 4096

    hipMemsetAsync(cnt, 0, (size_t)N * sizeof(int), stream);
    pack_B<<<56, 256, 0, stream>>>(Wm1, W1, Bp, Bp1);
    hist<<<(E + 255) / 256, 256, 0, stream>>>(dst, cnt, rank, E);
    scan1<<<NB, 256, 0, stream>>>(cnt, row_start, bsum, N);
    scan2<<<1, 256, 0, stream>>>(bsum, NB);
    scan3<<<NB, 256, 0, stream>>>(row_start, bsum, cnt, dinv, N);
    fill<<<(E + 255) / 256, 256, 0, stream>>>(src, dst, rank, row_start, csr, E);
    node_gemm_mfma<<<(NW + 3) / 4, 256, 0, stream>>>(x, Bp1, dinv, gbf, NW);
    gather_finalize<<<(N + 3) / 4, 256, 0, stream>>>((const unsigned int*)gbf, csr,
                                                     row_start, dinv, b1,
                                                     (unsigned int*)hbf, N);
    edge_mlp_mfma<<<1280, 256, 0, stream>>>(hbf, ea, src, dst, Bp,
                                            bm1, Wm2, bm2, out, E);
}